// Round 1
// baseline (2889.225 us; speedup 1.0000x reference)
//
#include <hip/hip_runtime.h>
#include <math.h>

#define HW   1024
#define NCH  768

// ---------------------------------------------------------------------------
// Kernel 1: 3x3 conv producing qkv = [q(256, scaled) | k(256) | v(256)]
// grid (48, 1, 12): x = co-tile (16 ch), z = img*4 + b. block = 256.
// out layout: [img][b][768][1024]
// ---------------------------------------------------------------------------
__global__ __launch_bounds__(256) void conv_qkv_kernel(
    const float* __restrict__ x1, const float* __restrict__ x2, const float* __restrict__ x12,
    const float* __restrict__ W1, const float* __restrict__ W2, const float* __restrict__ W3,
    const float* __restrict__ B1, const float* __restrict__ B2, const float* __restrict__ B3,
    float* __restrict__ out)
{
    const int co0 = blockIdx.x * 16;
    const int img = blockIdx.z >> 2;
    const int b   = blockIdx.z & 3;
    const float* x  = (img == 0) ? x1 : (img == 1) ? x2 : x12;
    const float* Wt = (img == 0) ? W1 : (img == 1) ? W2 : W3;
    const float* Bs = (img == 0) ? B1 : (img == 1) ? B2 : B3;

    __shared__ float xs[8][1156];     // [ci][(row+1)*34 + (col+1)], rows -1..32
    __shared__ float wsw[8][9][16];   // [ci][tap][co]

    const int tid  = threadIdx.x;
    const int xcol = tid & 31;
    const int trow = tid >> 5;        // 0..7

    float acc[4][16];
    #pragma unroll
    for (int py = 0; py < 4; ++py)
        #pragma unroll
        for (int co = 0; co < 16; ++co) acc[py][co] = 0.f;

    const float* xb = x + (size_t)b * 256 * HW;

    for (int ci0 = 0; ci0 < 256; ci0 += 8) {
        __syncthreads();
        for (int idx = tid; idx < 8 * 1156; idx += 256) {
            int ci  = idx / 1156;
            int rem = idx - ci * 1156;
            int rr  = rem / 34;
            int cc  = rem - rr * 34;
            int gr  = rr - 1, gc = cc - 1;
            float v = 0.f;
            if ((unsigned)gr < 32u && (unsigned)gc < 32u)
                v = xb[(size_t)(ci0 + ci) * HW + gr * 32 + gc];
            xs[ci][rem] = v;
        }
        for (int idx = tid; idx < 1152; idx += 256) {
            int co   = idx & 15;
            int rest = idx >> 4;        // ci*9 + t
            int ci   = rest / 9;
            int t    = rest - ci * 9;
            wsw[ci][t][co] = Wt[(size_t)(co0 + co) * (256 * 9) + (ci0 + ci) * 9 + t];
        }
        __syncthreads();

        #pragma unroll
        for (int ci = 0; ci < 8; ++ci) {
            #pragma unroll
            for (int t = 0; t < 9; ++t) {
                const int dy = t / 3, dx = t - (t / 3) * 3;
                const float4* wp = reinterpret_cast<const float4*>(&wsw[ci][t][0]);
                float4 w0 = wp[0], w1 = wp[1], w2 = wp[2], w3 = wp[3];
                #pragma unroll
                for (int py = 0; py < 4; ++py) {
                    float xvv = xs[ci][(trow + py * 8 + dy) * 34 + xcol + dx];
                    float* a = acc[py];
                    a[0]  = fmaf(w0.x, xvv, a[0]);  a[1]  = fmaf(w0.y, xvv, a[1]);
                    a[2]  = fmaf(w0.z, xvv, a[2]);  a[3]  = fmaf(w0.w, xvv, a[3]);
                    a[4]  = fmaf(w1.x, xvv, a[4]);  a[5]  = fmaf(w1.y, xvv, a[5]);
                    a[6]  = fmaf(w1.z, xvv, a[6]);  a[7]  = fmaf(w1.w, xvv, a[7]);
                    a[8]  = fmaf(w2.x, xvv, a[8]);  a[9]  = fmaf(w2.y, xvv, a[9]);
                    a[10] = fmaf(w2.z, xvv, a[10]); a[11] = fmaf(w2.w, xvv, a[11]);
                    a[12] = fmaf(w3.x, xvv, a[12]); a[13] = fmaf(w3.y, xvv, a[13]);
                    a[14] = fmaf(w3.z, xvv, a[14]); a[15] = fmaf(w3.w, xvv, a[15]);
                }
            }
        }
    }

    float* ob = out + ((size_t)img * 4 + b) * NCH * HW;
    #pragma unroll
    for (int co = 0; co < 16; ++co) {
        int ch = co0 + co;
        float bias  = Bs[ch];
        float scale = (ch < 256) ? 0.17677669529663687f : 1.0f;  // DKH^-0.5 on q only
        #pragma unroll
        for (int py = 0; py < 4; ++py) {
            int rr = trow + py * 8;
            ob[(size_t)ch * HW + rr * 32 + xcol] = (acc[py][co] + bias) * scale;
        }
    }
}

// ---------------------------------------------------------------------------
// Kernel 2: fused attention (online softmax), thread-per-query.
// grid (4, 32, 3): x = q-block(256 q), y = b*8+n, z = branch. block = 256.
// rel bias(q=(r,c), k=(z,m)) = dot(qv, krw[m-c+31]) + dot(qv, krh[z-r+31])
// Output with bug-faithful reshape: y[br][b][n*32 + (q>>5)][(q&31)*32 + d]
// ---------------------------------------------------------------------------
__global__ __launch_bounds__(256) void attn_kernel(
    const float* __restrict__ qkvw,
    const float* __restrict__ krw, const float* __restrict__ krh,
    float* __restrict__ yw)
{
    const int br  = blockIdx.z;
    const int b   = blockIdx.y >> 3;
    const int n   = blockIdx.y & 7;
    const int tid = threadIdx.x;
    const int q   = blockIdx.x * 256 + tid;
    const int r   = q >> 5;
    const int c   = q & 31;

    const size_t img_stride = (size_t)4 * NCH * HW;
    const float* g0 = qkvw + (size_t)b * NCH * HW;   // x1, batch b
    const float* g1 = g0 + img_stride;               // x2
    const float* g2 = g1 + img_stride;               // x12

    const float* Q; const float* Ka; const float* Kb = nullptr; const float* V;
    if (br == 0)      { Q = g0 + (size_t)(n*32)*HW; Ka = g2 + (size_t)(256 + n*32)*HW; V = g0 + (size_t)(512 + n*32)*HW; }
    else if (br == 1) { Q = g1 + (size_t)(n*32)*HW; Ka = g2 + (size_t)(256 + n*32)*HW; V = g1 + (size_t)(512 + n*32)*HW; }
    else              { Q = g2 + (size_t)(n*32)*HW; Ka = g0 + (size_t)(256 + n*32)*HW;
                        Kb = g1 + (size_t)(256 + n*32)*HW; V = g2 + (size_t)(512 + n*32)*HW; }

    __shared__ float ks[32][32];         // [d][m]
    __shared__ float vs[32][32];         // [d][m]
    __shared__ float rwl[63 * 33 + 1];   // stride 33 => conflict-free gathers
    __shared__ float rhl[63 * 33 + 1];

    float qv[32];
    #pragma unroll
    for (int d = 0; d < 32; ++d) qv[d] = Q[(size_t)d * HW + q];

    float rwdot[32];
    if (br == 0) {
        for (int idx = tid; idx < 63 * 32; idx += 256) {
            int mp = idx >> 5, d = idx & 31;
            rwl[mp * 33 + d] = krw[idx];
            rhl[mp * 33 + d] = krh[idx];
        }
        __syncthreads();
        #pragma unroll
        for (int m = 0; m < 32; ++m) {
            int mp = m + 31 - c;
            float s = 0.f;
            #pragma unroll
            for (int d = 0; d < 32; ++d) s = fmaf(qv[d], rwl[mp * 33 + d], s);
            rwdot[m] = s;
        }
    }

    float m_run = -INFINITY, l_run = 0.f;
    float acc[32];
    #pragma unroll
    for (int d = 0; d < 32; ++d) acc[d] = 0.f;

    for (int z = 0; z < 32; ++z) {       // key tile = image row z (32 keys)
        __syncthreads();
        for (int idx = tid; idx < 1024; idx += 256) {
            int d = idx >> 5, m = idx & 31;
            float kvv = Ka[(size_t)d * HW + z * 32 + m];
            if (br == 2) kvv -= Kb[(size_t)d * HW + z * 32 + m];
            ks[d][m] = kvv;
            vs[d][m] = V[(size_t)d * HW + z * 32 + m];
        }
        __syncthreads();

        float sv[32];
        if (br == 0) {
            int zp = z + 31 - r;
            float rh_z = 0.f;
            #pragma unroll
            for (int d = 0; d < 32; ++d) rh_z = fmaf(qv[d], rhl[zp * 33 + d], rh_z);
            #pragma unroll
            for (int m = 0; m < 32; ++m) sv[m] = rwdot[m] + rh_z;
        } else {
            #pragma unroll
            for (int m = 0; m < 32; ++m) sv[m] = 0.f;
        }

        #pragma unroll
        for (int d = 0; d < 32; ++d) {
            const float4* kp = reinterpret_cast<const float4*>(&ks[d][0]);
            float qd = qv[d];
            #pragma unroll
            for (int mq = 0; mq < 8; ++mq) {
                float4 k4 = kp[mq];
                sv[mq*4+0] = fmaf(qd, k4.x, sv[mq*4+0]);
                sv[mq*4+1] = fmaf(qd, k4.y, sv[mq*4+1]);
                sv[mq*4+2] = fmaf(qd, k4.z, sv[mq*4+2]);
                sv[mq*4+3] = fmaf(qd, k4.w, sv[mq*4+3]);
            }
        }

        float tmax = sv[0];
        #pragma unroll
        for (int m = 1; m < 32; ++m) tmax = fmaxf(tmax, sv[m]);
        float m_new = fmaxf(m_run, tmax);
        float sc = __expf(m_run - m_new);
        float psum = 0.f;
        #pragma unroll
        for (int m = 0; m < 32; ++m) { sv[m] = __expf(sv[m] - m_new); psum += sv[m]; }
        l_run = l_run * sc + psum;
        m_run = m_new;

        #pragma unroll
        for (int d = 0; d < 32; ++d) {
            const float4* vp = reinterpret_cast<const float4*>(&vs[d][0]);
            float a = acc[d] * sc;
            #pragma unroll
            for (int mq = 0; mq < 8; ++mq) {
                float4 v4 = vp[mq];
                a = fmaf(sv[mq*4+0], v4.x, a);
                a = fmaf(sv[mq*4+1], v4.y, a);
                a = fmaf(sv[mq*4+2], v4.z, a);
                a = fmaf(sv[mq*4+3], v4.w, a);
            }
            acc[d] = a;
        }
    }

    float inv = 1.0f / l_run;
    float* yb = yw + (((size_t)(br * 4 + b)) * 256 + (n * 32 + r)) * HW + c * 32;
    #pragma unroll
    for (int d = 0; d < 32; d += 4) {
        float4 o = make_float4(acc[d]*inv, acc[d+1]*inv, acc[d+2]*inv, acc[d+3]*inv);
        *reinterpret_cast<float4*>(yb + d) = o;
    }
}

// ---------------------------------------------------------------------------
// Kernel 3: 1x1 conv (attn_out1 applied to all three branches)
// grid (16, 4, 12): x = co-tile(16), y = pixel-tile(256), z = br*4+b.
// ---------------------------------------------------------------------------
__global__ __launch_bounds__(256) void conv1x1_kernel(
    const float* __restrict__ yw, const float* __restrict__ Wo,
    const float* __restrict__ bo, float* __restrict__ out)
{
    const int co0  = blockIdx.x * 16;
    const int p0   = blockIdx.y * 256;
    const int slab = blockIdx.z;     // br*4 + b
    const float* yb = yw + (size_t)slab * 256 * HW;
    float* ob       = out + (size_t)slab * 256 * HW;

    __shared__ float ys[32][256];
    __shared__ float wsl[32][16];

    const int tid = threadIdx.x;
    float acc[16];
    #pragma unroll
    for (int co = 0; co < 16; ++co) acc[co] = 0.f;

    for (int ci0 = 0; ci0 < 256; ci0 += 32) {
        __syncthreads();
        for (int idx = tid; idx < 32 * 256; idx += 256) {
            int ci = idx >> 8, p = idx & 255;
            ys[ci][p] = yb[(size_t)(ci0 + ci) * HW + p0 + p];
        }
        for (int idx = tid; idx < 512; idx += 256) {
            int ci = idx >> 4, co = idx & 15;
            wsl[ci][co] = Wo[(size_t)(co0 + co) * 256 + ci0 + ci];
        }
        __syncthreads();
        #pragma unroll
        for (int ci = 0; ci < 32; ++ci) {
            float xv = ys[ci][tid];
            const float4* wp = reinterpret_cast<const float4*>(&wsl[ci][0]);
            float4 w0 = wp[0], w1 = wp[1], w2 = wp[2], w3 = wp[3];
            acc[0]  = fmaf(w0.x, xv, acc[0]);  acc[1]  = fmaf(w0.y, xv, acc[1]);
            acc[2]  = fmaf(w0.z, xv, acc[2]);  acc[3]  = fmaf(w0.w, xv, acc[3]);
            acc[4]  = fmaf(w1.x, xv, acc[4]);  acc[5]  = fmaf(w1.y, xv, acc[5]);
            acc[6]  = fmaf(w1.z, xv, acc[6]);  acc[7]  = fmaf(w1.w, xv, acc[7]);
            acc[8]  = fmaf(w2.x, xv, acc[8]);  acc[9]  = fmaf(w2.y, xv, acc[9]);
            acc[10] = fmaf(w2.z, xv, acc[10]); acc[11] = fmaf(w2.w, xv, acc[11]);
            acc[12] = fmaf(w3.x, xv, acc[12]); acc[13] = fmaf(w3.y, xv, acc[13]);
            acc[14] = fmaf(w3.z, xv, acc[14]); acc[15] = fmaf(w3.w, xv, acc[15]);
        }
    }
    #pragma unroll
    for (int co = 0; co < 16; ++co)
        ob[(size_t)(co0 + co) * HW + p0 + tid] = acc[co] + bo[co0 + co];
}

// ---------------------------------------------------------------------------
extern "C" void kernel_launch(void* const* d_in, const int* in_sizes, int n_in,
                              void* d_out, int out_size, void* d_ws, size_t ws_size,
                              hipStream_t stream)
{
    const float* x1   = (const float*)d_in[0];
    const float* x2   = (const float*)d_in[1];
    const float* x12  = (const float*)d_in[2];
    const float* Wq1  = (const float*)d_in[3];
    const float* bq1  = (const float*)d_in[4];
    const float* Wq2  = (const float*)d_in[5];
    const float* bq2  = (const float*)d_in[6];
    const float* Wq12 = (const float*)d_in[7];
    const float* bq12 = (const float*)d_in[8];
    const float* Wo   = (const float*)d_in[9];
    const float* bo   = (const float*)d_in[10];
    const float* krw  = (const float*)d_in[11];
    const float* krh  = (const float*)d_in[12];

    float* qkvw = (float*)d_ws;                         // [3][4][768][1024] fp32
    float* yw   = qkvw + (size_t)3 * 4 * NCH * HW;      // [3][4][256][1024] fp32
    float* outf = (float*)d_out;                        // [3][4][256][1024] fp32

    hipLaunchKernelGGL(conv_qkv_kernel, dim3(48, 1, 12), dim3(256), 0, stream,
                       x1, x2, x12, Wq1, Wq2, Wq12, bq1, bq2, bq12, qkvw);
    hipLaunchKernelGGL(attn_kernel, dim3(4, 32, 3), dim3(256), 0, stream,
                       qkvw, krw, krh, yw);
    hipLaunchKernelGGL(conv1x1_kernel, dim3(16, 4, 12), dim3(256), 0, stream,
                       yw, Wo, bo, outf);
}

// Round 2
// 1513.542 us; speedup vs baseline: 1.9089x; 1.9089x over previous
//
#include <hip/hip_runtime.h>
#include <math.h>

#define HW   1024
#define NCH  768

typedef __bf16 bf16x8 __attribute__((ext_vector_type(8)));
typedef float f32x4 __attribute__((ext_vector_type(4)));
typedef unsigned short ushort_t;

__device__ __forceinline__ ushort_t f2bf(float f) {
    unsigned u = __builtin_bit_cast(unsigned, f);
    u += 0x7fffu + ((u >> 16) & 1u);           // round-to-nearest-even
    return (ushort_t)(u >> 16);
}

#define GLOAD16(g, l) __builtin_amdgcn_global_load_lds( \
    (const __attribute__((address_space(1))) void*)(g), \
    (__attribute__((address_space(3))) void*)(l), 16, 0, 0)

// ---------------------------------------------------------------------------
// prep_x: x [img][b][256][32][32] fp32 -> xpadT [slab][34][34][256] bf16,
// zero halo (memset beforehand), ci innermost for contiguous B staging.
// grid (32 rows, 12 slabs), block 256.
// ---------------------------------------------------------------------------
__global__ __launch_bounds__(256) void prep_x_kernel(
    const float* __restrict__ x1, const float* __restrict__ x2, const float* __restrict__ x12,
    ushort_t* __restrict__ xpadT)
{
    const int row  = blockIdx.x;          // 0..31
    const int slab = blockIdx.y;          // img*4 + b
    const int img  = slab >> 2, b = slab & 3;
    const float* x  = (img == 0) ? x1 : (img == 1) ? x2 : x12;
    const float* xb = x + (size_t)b * 256 * HW + row * 32;

    __shared__ float xs[32][257];
    const int tid = threadIdx.x;
    for (int idx = tid; idx < 256 * 32; idx += 256) {
        int ci = idx >> 5, col = idx & 31;
        xs[col][ci] = xb[(size_t)ci * HW + col];
    }
    __syncthreads();
    ushort_t* ob = xpadT + ((size_t)slab * 34 * 34 + (size_t)(row + 1) * 34 + 1) * 256;
    for (int col = 0; col < 32; ++col)
        ob[(size_t)col * 256 + tid] = f2bf(xs[col][tid]);
}

// ---------------------------------------------------------------------------
// prep_w: W [img][768][256*9] fp32 -> pre-swizzled bf16 A-tiles
// Wb[img][t][cic][coc][4096 elem] laid out exactly as the conv LDS image:
// element = row*32 + phys_slot*8 + e, phys = s ^ ((row^(row>>2))&3),
// value = W[coc*128+row][(cic*32 + s*8 + e)*9 + t].
// thread per (img, co, ci), 9 taps each. grid 2304 x 256.
// ---------------------------------------------------------------------------
__global__ __launch_bounds__(256) void prep_w_kernel(
    const float* __restrict__ W1, const float* __restrict__ W2, const float* __restrict__ W3,
    ushort_t* __restrict__ Wb)
{
    int g = blockIdx.x * 256 + threadIdx.x;
    if (g >= 3 * 768 * 256) return;
    int ci  = g & 255;
    int co  = (g >> 8) % 768;
    int img = g / (768 * 256);
    const float* Wt  = (img == 0) ? W1 : (img == 1) ? W2 : W3;
    const float* src = Wt + (size_t)co * (256 * 9) + ci * 9;

    int coc = co >> 7, row = co & 127;
    int cic = ci >> 5;
    int cil = ci & 31;
    int s = cil >> 3, e = cil & 7;
    int phys  = s ^ ((row ^ (row >> 2)) & 3);
    int inner = row * 32 + phys * 8 + e;
    #pragma unroll
    for (int t = 0; t < 9; ++t) {
        size_t tile = (((size_t)img * 9 + t) * 8 + cic) * 6 + coc;
        Wb[tile * 4096 + inner] = f2bf(src[t]);
    }
}

// ---------------------------------------------------------------------------
// conv_mfma: implicit-GEMM 3x3 conv, bf16 MFMA 16x16x32, fp32 epilogue.
// Per slab: Y[co=768][p=1024] = sum_{t,ci} W[co][ci,t] * xpad[ci][p shifted].
// Block: 128co x 128p tile, 4 waves (2x2), K-chunk = 32 (one tap, 32 ci),
// 72 chunks, double-buffered LDS, global_load_lds staging.
// grid (8 p-tiles, 6 co-tiles, 12 slabs), block 256.
// Epilogue writes fp32 qkv[slab][ch][p] with bias + q-scale (unchanged layout).
// ---------------------------------------------------------------------------
__global__ __launch_bounds__(256) void conv_mfma_kernel(
    const ushort_t* __restrict__ Wb, const ushort_t* __restrict__ xpadT,
    const float* __restrict__ B1, const float* __restrict__ B2, const float* __restrict__ B3,
    float* __restrict__ out)
{
    const int bx   = blockIdx.x;      // p-tile
    const int by   = blockIdx.y;      // co-tile
    const int slab = blockIdx.z;      // img*4+b
    const int img  = slab >> 2;
    const float* Bs_bias = (img == 0) ? B1 : (img == 1) ? B2 : B3;

    __shared__ ushort_t As[2][4096];   // [128 co][4 slot][8] swizzled
    __shared__ ushort_t Bsh[2][4096];  // [128 p ][4 slot][8] swizzled

    const int tid  = threadIdx.x;
    const int lane = tid & 63;
    const int wid  = tid >> 6;
    const int wr   = wid >> 1, wc = wid & 1;

    const ushort_t* WbI = Wb + (size_t)img * 9 * 8 * 6 * 4096;
    const ushort_t* xpI = xpadT + (size_t)slab * 34 * 34 * 256;
    const int r0 = bx * 4;

    // B-staging dest decompose (dest bytes o = r*4096 + tid*16)
    int pB[2], cibase[2];
    #pragma unroll
    for (int r = 0; r < 2; ++r) {
        int o    = r * 4096 + tid * 16;
        int p    = o >> 6;
        int phys = (o >> 4) & 3;
        int s    = phys ^ ((p ^ (p >> 2)) & 3);
        pB[r]     = p;
        cibase[r] = s * 8;
    }

    f32x4 acc[4][4];
    #pragma unroll
    for (int m = 0; m < 4; ++m)
        #pragma unroll
        for (int n = 0; n < 4; ++n) acc[m][n] = (f32x4){0.f, 0.f, 0.f, 0.f};

    // fragment read offsets (ushort index), swizzled
    int aoff[4], boff[4];
    #pragma unroll
    for (int m = 0; m < 4; ++m) {
        int row  = wr * 64 + m * 16 + (lane & 15);
        int phys = (lane >> 4) ^ ((row ^ (row >> 2)) & 3);
        aoff[m] = row * 32 + phys * 8;
    }
    #pragma unroll
    for (int n = 0; n < 4; ++n) {
        int row  = wc * 64 + n * 16 + (lane & 15);
        int phys = (lane >> 4) ^ ((row ^ (row >> 2)) & 3);
        boff[n] = row * 32 + phys * 8;
    }

    auto stage = [&](int kk, int buf) {
        int t = kk >> 3, cic = kk & 7;
        int dy = t / 3, dx = t - dy * 3;
        const ushort_t* wtile = WbI + ((size_t)(t * 8 + cic) * 6 + by) * 4096;
        #pragma unroll
        for (int r = 0; r < 2; ++r) {
            GLOAD16(wtile + r * 2048 + tid * 8, (ushort_t*)As[buf] + r * 2048 + tid * 8);
        }
        #pragma unroll
        for (int r = 0; r < 2; ++r) {
            int p  = pB[r];
            int pr = p >> 5, c = p & 31;
            const ushort_t* src = xpI
                + ((size_t)((r0 + pr + dy) * 34 + (c + dx))) * 256
                + cic * 32 + cibase[r];
            GLOAD16(src, (ushort_t*)Bsh[buf] + r * 2048 + tid * 8);
        }
    };

    stage(0, 0);
    asm volatile("s_waitcnt vmcnt(0)" ::: "memory");
    __builtin_amdgcn_s_barrier();

    for (int kk = 0; kk < 72; ++kk) {
        int cur = kk & 1;
        if (kk < 71) stage(kk + 1, cur ^ 1);

        const ushort_t* Ab = As[cur];
        const ushort_t* Bb = Bsh[cur];
        bf16x8 af[4], bfr[4];
        #pragma unroll
        for (int m = 0; m < 4; ++m) af[m] = *(const bf16x8*)(Ab + aoff[m]);
        #pragma unroll
        for (int n = 0; n < 4; ++n) bfr[n] = *(const bf16x8*)(Bb + boff[n]);

        #pragma unroll
        for (int m = 0; m < 4; ++m)
            #pragma unroll
            for (int n = 0; n < 4; ++n)
                acc[m][n] = __builtin_amdgcn_mfma_f32_16x16x32_bf16(af[m], bfr[n], acc[m][n], 0, 0, 0);

        asm volatile("s_waitcnt vmcnt(0)" ::: "memory");
        __builtin_amdgcn_s_barrier();
    }

    // epilogue: D[row=co][col=p], row = (lane>>4)*4 + reg, col = lane&15
    const int co_base = by * 128 + wr * 64;
    const int p_base  = bx * 128 + wc * 64;
    float* ob = out + (size_t)slab * NCH * HW;
    const int rsub = (lane >> 4) * 4;
    const int csub = lane & 15;
    #pragma unroll
    for (int m = 0; m < 4; ++m) {
        #pragma unroll
        for (int rg = 0; rg < 4; ++rg) {
            int ch = co_base + m * 16 + rsub + rg;
            float bias  = Bs_bias[ch];
            float scale = (ch < 256) ? 0.17677669529663687f : 1.0f;  // DKH^-0.5 on q
            #pragma unroll
            for (int n = 0; n < 4; ++n) {
                int p = p_base + n * 16 + csub;
                ob[(size_t)ch * HW + p] = (acc[m][n][rg] + bias) * scale;
            }
        }
    }
}

// ---------------------------------------------------------------------------
// Kernel: fused attention (online softmax), thread-per-query. UNCHANGED (R1).
// ---------------------------------------------------------------------------
__global__ __launch_bounds__(256) void attn_kernel(
    const float* __restrict__ qkvw,
    const float* __restrict__ krw, const float* __restrict__ krh,
    float* __restrict__ yw)
{
    const int br  = blockIdx.z;
    const int b   = blockIdx.y >> 3;
    const int n   = blockIdx.y & 7;
    const int tid = threadIdx.x;
    const int q   = blockIdx.x * 256 + tid;
    const int r   = q >> 5;
    const int c   = q & 31;

    const size_t img_stride = (size_t)4 * NCH * HW;
    const float* g0 = qkvw + (size_t)b * NCH * HW;
    const float* g1 = g0 + img_stride;
    const float* g2 = g1 + img_stride;

    const float* Q; const float* Ka; const float* Kb = nullptr; const float* V;
    if (br == 0)      { Q = g0 + (size_t)(n*32)*HW; Ka = g2 + (size_t)(256 + n*32)*HW; V = g0 + (size_t)(512 + n*32)*HW; }
    else if (br == 1) { Q = g1 + (size_t)(n*32)*HW; Ka = g2 + (size_t)(256 + n*32)*HW; V = g1 + (size_t)(512 + n*32)*HW; }
    else              { Q = g2 + (size_t)(n*32)*HW; Ka = g0 + (size_t)(256 + n*32)*HW;
                        Kb = g1 + (size_t)(256 + n*32)*HW; V = g2 + (size_t)(512 + n*32)*HW; }

    __shared__ float ks[32][32];
    __shared__ float vs[32][32];
    __shared__ float rwl[63 * 33 + 1];
    __shared__ float rhl[63 * 33 + 1];

    float qv[32];
    #pragma unroll
    for (int d = 0; d < 32; ++d) qv[d] = Q[(size_t)d * HW + q];

    float rwdot[32];
    if (br == 0) {
        for (int idx = tid; idx < 63 * 32; idx += 256) {
            int mp = idx >> 5, d = idx & 31;
            rwl[mp * 33 + d] = krw[idx];
            rhl[mp * 33 + d] = krh[idx];
        }
        __syncthreads();
        #pragma unroll
        for (int m = 0; m < 32; ++m) {
            int mp = m + 31 - c;
            float s = 0.f;
            #pragma unroll
            for (int d = 0; d < 32; ++d) s = fmaf(qv[d], rwl[mp * 33 + d], s);
            rwdot[m] = s;
        }
    }

    float m_run = -INFINITY, l_run = 0.f;
    float acc[32];
    #pragma unroll
    for (int d = 0; d < 32; ++d) acc[d] = 0.f;

    for (int z = 0; z < 32; ++z) {
        __syncthreads();
        for (int idx = tid; idx < 1024; idx += 256) {
            int d = idx >> 5, m = idx & 31;
            float kvv = Ka[(size_t)d * HW + z * 32 + m];
            if (br == 2) kvv -= Kb[(size_t)d * HW + z * 32 + m];
            ks[d][m] = kvv;
            vs[d][m] = V[(size_t)d * HW + z * 32 + m];
        }
        __syncthreads();

        float sv[32];
        if (br == 0) {
            int zp = z + 31 - r;
            float rh_z = 0.f;
            #pragma unroll
            for (int d = 0; d < 32; ++d) rh_z = fmaf(qv[d], rhl[zp * 33 + d], rh_z);
            #pragma unroll
            for (int m = 0; m < 32; ++m) sv[m] = rwdot[m] + rh_z;
        } else {
            #pragma unroll
            for (int m = 0; m < 32; ++m) sv[m] = 0.f;
        }

        #pragma unroll
        for (int d = 0; d < 32; ++d) {
            const float4* kp = reinterpret_cast<const float4*>(&ks[d][0]);
            float qd = qv[d];
            #pragma unroll
            for (int mq = 0; mq < 8; ++mq) {
                float4 k4 = kp[mq];
                sv[mq*4+0] = fmaf(qd, k4.x, sv[mq*4+0]);
                sv[mq*4+1] = fmaf(qd, k4.y, sv[mq*4+1]);
                sv[mq*4+2] = fmaf(qd, k4.z, sv[mq*4+2]);
                sv[mq*4+3] = fmaf(qd, k4.w, sv[mq*4+3]);
            }
        }

        float tmax = sv[0];
        #pragma unroll
        for (int m = 1; m < 32; ++m) tmax = fmaxf(tmax, sv[m]);
        float m_new = fmaxf(m_run, tmax);
        float sc = __expf(m_run - m_new);
        float psum = 0.f;
        #pragma unroll
        for (int m = 0; m < 32; ++m) { sv[m] = __expf(sv[m] - m_new); psum += sv[m]; }
        l_run = l_run * sc + psum;
        m_run = m_new;

        #pragma unroll
        for (int d = 0; d < 32; ++d) {
            const float4* vp = reinterpret_cast<const float4*>(&vs[d][0]);
            float a = acc[d] * sc;
            #pragma unroll
            for (int mq = 0; mq < 8; ++mq) {
                float4 v4 = vp[mq];
                a = fmaf(sv[mq*4+0], v4.x, a);
                a = fmaf(sv[mq*4+1], v4.y, a);
                a = fmaf(sv[mq*4+2], v4.z, a);
                a = fmaf(sv[mq*4+3], v4.w, a);
            }
            acc[d] = a;
        }
    }

    float inv = 1.0f / l_run;
    float* yb = yw + (((size_t)(br * 4 + b)) * 256 + (n * 32 + r)) * HW + c * 32;
    #pragma unroll
    for (int d = 0; d < 32; d += 4) {
        float4 o = make_float4(acc[d]*inv, acc[d+1]*inv, acc[d+2]*inv, acc[d+3]*inv);
        *reinterpret_cast<float4*>(yb + d) = o;
    }
}

// ---------------------------------------------------------------------------
// Kernel: 1x1 conv. UNCHANGED (R1).
// ---------------------------------------------------------------------------
__global__ __launch_bounds__(256) void conv1x1_kernel(
    const float* __restrict__ yw, const float* __restrict__ Wo,
    const float* __restrict__ bo, float* __restrict__ out)
{
    const int co0  = blockIdx.x * 16;
    const int p0   = blockIdx.y * 256;
    const int slab = blockIdx.z;
    const float* yb = yw + (size_t)slab * 256 * HW;
    float* ob       = out + (size_t)slab * 256 * HW;

    __shared__ float ys[32][256];
    __shared__ float wsl[32][16];

    const int tid = threadIdx.x;
    float acc[16];
    #pragma unroll
    for (int co = 0; co < 16; ++co) acc[co] = 0.f;

    for (int ci0 = 0; ci0 < 256; ci0 += 32) {
        __syncthreads();
        for (int idx = tid; idx < 32 * 256; idx += 256) {
            int ci = idx >> 8, p = idx & 255;
            ys[ci][p] = yb[(size_t)(ci0 + ci) * HW + p0 + p];
        }
        for (int idx = tid; idx < 512; idx += 256) {
            int ci = idx >> 4, co = idx & 15;
            wsl[ci][co] = Wo[(size_t)(co0 + co) * 256 + ci0 + ci];
        }
        __syncthreads();
        #pragma unroll
        for (int ci = 0; ci < 32; ++ci) {
            float xv = ys[ci][tid];
            const float4* wp = reinterpret_cast<const float4*>(&wsl[ci][0]);
            float4 w0 = wp[0], w1 = wp[1], w2 = wp[2], w3 = wp[3];
            acc[0]  = fmaf(w0.x, xv, acc[0]);  acc[1]  = fmaf(w0.y, xv, acc[1]);
            acc[2]  = fmaf(w0.z, xv, acc[2]);  acc[3]  = fmaf(w0.w, xv, acc[3]);
            acc[4]  = fmaf(w1.x, xv, acc[4]);  acc[5]  = fmaf(w1.y, xv, acc[5]);
            acc[6]  = fmaf(w1.z, xv, acc[6]);  acc[7]  = fmaf(w1.w, xv, acc[7]);
            acc[8]  = fmaf(w2.x, xv, acc[8]);  acc[9]  = fmaf(w2.y, xv, acc[9]);
            acc[10] = fmaf(w2.z, xv, acc[10]); acc[11] = fmaf(w2.w, xv, acc[11]);
            acc[12] = fmaf(w3.x, xv, acc[12]); acc[13] = fmaf(w3.y, xv, acc[13]);
            acc[14] = fmaf(w3.z, xv, acc[14]); acc[15] = fmaf(w3.w, xv, acc[15]);
        }
    }
    #pragma unroll
    for (int co = 0; co < 16; ++co)
        ob[(size_t)(co0 + co) * HW + p0 + tid] = acc[co] + bo[co0 + co];
}

// ---------------------------------------------------------------------------
extern "C" void kernel_launch(void* const* d_in, const int* in_sizes, int n_in,
                              void* d_out, int out_size, void* d_ws, size_t ws_size,
                              hipStream_t stream)
{
    const float* x1   = (const float*)d_in[0];
    const float* x2   = (const float*)d_in[1];
    const float* x12  = (const float*)d_in[2];
    const float* Wq1  = (const float*)d_in[3];
    const float* bq1  = (const float*)d_in[4];
    const float* Wq2  = (const float*)d_in[5];
    const float* bq2  = (const float*)d_in[6];
    const float* Wq12 = (const float*)d_in[7];
    const float* bq12 = (const float*)d_in[8];
    const float* Wo   = (const float*)d_in[9];
    const float* bo   = (const float*)d_in[10];
    const float* krw  = (const float*)d_in[11];
    const float* krh  = (const float*)d_in[12];

    // workspace layout (55.5 MB):
    //   qkvw fp32 [12][768][1024]                        37,748,736 B
    //   region1: Wb bf16 (10,616,832 B) + xpadT bf16 (7,102,464 B)
    //            yw fp32 [12][256][1024] ALIASES region1 (written after conv
    //            has consumed Wb/xpadT; both rebuilt every call)
    char* base = (char*)d_ws;
    float*    qkvw  = (float*)base;
    char*     reg1  = base + (size_t)12 * NCH * HW * 4;
    ushort_t* Wb    = (ushort_t*)reg1;
    ushort_t* xpadT = (ushort_t*)(reg1 + (size_t)3 * 9 * 8 * 6 * 4096 * 2);
    float*    yw    = (float*)reg1;
    float*    outf  = (float*)d_out;

    const size_t xpad_bytes = (size_t)12 * 34 * 34 * 256 * 2;
    hipMemsetAsync(xpadT, 0, xpad_bytes, stream);

    hipLaunchKernelGGL(prep_x_kernel, dim3(32, 12), dim3(256), 0, stream,
                       x1, x2, x12, xpadT);
    hipLaunchKernelGGL(prep_w_kernel, dim3(2304), dim3(256), 0, stream,
                       Wq1, Wq2, Wq12, Wb);
    hipLaunchKernelGGL(conv_mfma_kernel, dim3(8, 6, 12), dim3(256), 0, stream,
                       Wb, xpadT, bq1, bq2, bq12, qkvw);
    hipLaunchKernelGGL(attn_kernel, dim3(4, 32, 3), dim3(256), 0, stream,
                       qkvw, krw, krh, yw);
    hipLaunchKernelGGL(conv1x1_kernel, dim3(16, 4, 12), dim3(256), 0, stream,
                       yw, Wo, bo, outf);
}

// Round 4
// 246.584 us; speedup vs baseline: 11.7170x; 6.1380x over previous
//
#include <hip/hip_runtime.h>
#include <math.h>

#define HW   1024
#define NCH  768

typedef __bf16 bf16x8 __attribute__((ext_vector_type(8)));
typedef float f32x4 __attribute__((ext_vector_type(4)));
typedef unsigned short ushort_t;

__device__ __forceinline__ ushort_t f2bf(float f) {
    unsigned u = __builtin_bit_cast(unsigned, f);
    u += 0x7fffu + ((u >> 16) & 1u);           // round-to-nearest-even
    return (ushort_t)(u >> 16);
}
__device__ __forceinline__ float bf2f(ushort_t s) {
    unsigned u = ((unsigned)s) << 16;
    return __builtin_bit_cast(float, u);
}

#define GLOAD16(g, l) __builtin_amdgcn_global_load_lds( \
    (const __attribute__((address_space(1))) void*)(g), \
    (__attribute__((address_space(3))) void*)(l), 16, 0, 0)

// ---------------------------------------------------------------------------
// prep_x: x [img][b][256][32][32] fp32 -> xpadT [slab][34][34][256] bf16.
// ---------------------------------------------------------------------------
__global__ __launch_bounds__(256) void prep_x_kernel(
    const float* __restrict__ x1, const float* __restrict__ x2, const float* __restrict__ x12,
    ushort_t* __restrict__ xpadT)
{
    const int row  = blockIdx.x;
    const int slab = blockIdx.y;
    const int img  = slab >> 2, b = slab & 3;
    const float* x  = (img == 0) ? x1 : (img == 1) ? x2 : x12;
    const float* xb = x + (size_t)b * 256 * HW + row * 32;

    __shared__ float xs[32][257];
    const int tid = threadIdx.x;
    for (int idx = tid; idx < 256 * 32; idx += 256) {
        int ci = idx >> 5, col = idx & 31;
        xs[col][ci] = xb[(size_t)ci * HW + col];
    }
    __syncthreads();
    ushort_t* ob = xpadT + ((size_t)slab * 34 * 34 + (size_t)(row + 1) * 34 + 1) * 256;
    for (int col = 0; col < 32; ++col)
        ob[(size_t)col * 256 + tid] = f2bf(xs[col][tid]);
}

// ---------------------------------------------------------------------------
// prep_w: pre-swizzled bf16 A-tiles for conv (unchanged).
// ---------------------------------------------------------------------------
__global__ __launch_bounds__(256) void prep_w_kernel(
    const float* __restrict__ W1, const float* __restrict__ W2, const float* __restrict__ W3,
    ushort_t* __restrict__ Wb)
{
    int g = blockIdx.x * 256 + threadIdx.x;
    if (g >= 3 * 768 * 256) return;
    int ci  = g & 255;
    int co  = (g >> 8) % 768;
    int img = g / (768 * 256);
    const float* Wt  = (img == 0) ? W1 : (img == 1) ? W2 : W3;
    const float* src = Wt + (size_t)co * (256 * 9) + ci * 9;

    int coc = co >> 7, row = co & 127;
    int cic = ci >> 5;
    int cil = ci & 31;
    int s = cil >> 3, e = cil & 7;
    int phys  = s ^ ((row ^ (row >> 2)) & 3);
    int inner = row * 32 + phys * 8 + e;
    #pragma unroll
    for (int t = 0; t < 9; ++t) {
        size_t tile = (((size_t)img * 9 + t) * 8 + cic) * 6 + coc;
        Wb[tile * 4096 + inner] = f2bf(src[t]);
    }
}

// ---------------------------------------------------------------------------
// conv_mfma: implicit-GEMM 3x3 conv. Epilogue splits outputs:
//   ch<256  -> Qf fp32 [slab][256][1024] (bias + q-scale, FULL precision)
//   256-511 -> Kb bf16 [slab][256][1024]
//   512-767 -> Vb bf16 [slab][256][1024]
// ---------------------------------------------------------------------------
__global__ __launch_bounds__(256) void conv_mfma_kernel(
    const ushort_t* __restrict__ Wb, const ushort_t* __restrict__ xpadT,
    const float* __restrict__ B1, const float* __restrict__ B2, const float* __restrict__ B3,
    float* __restrict__ Qf, ushort_t* __restrict__ Kb, ushort_t* __restrict__ Vb)
{
    const int bx   = blockIdx.x;
    const int by   = blockIdx.y;
    const int slab = blockIdx.z;
    const int img  = slab >> 2;
    const float* Bs_bias = (img == 0) ? B1 : (img == 1) ? B2 : B3;

    __shared__ ushort_t As[2][4096];
    __shared__ ushort_t Bsh[2][4096];

    const int tid  = threadIdx.x;
    const int lane = tid & 63;
    const int wid  = tid >> 6;
    const int wr   = wid >> 1, wc = wid & 1;

    const ushort_t* WbI = Wb + (size_t)img * 9 * 8 * 6 * 4096;
    const ushort_t* xpI = xpadT + (size_t)slab * 34 * 34 * 256;
    const int r0 = bx * 4;

    int pB[2], cibase[2];
    #pragma unroll
    for (int r = 0; r < 2; ++r) {
        int o    = r * 4096 + tid * 16;
        int p    = o >> 6;
        int phys = (o >> 4) & 3;
        int s    = phys ^ ((p ^ (p >> 2)) & 3);
        pB[r]     = p;
        cibase[r] = s * 8;
    }

    f32x4 acc[4][4];
    #pragma unroll
    for (int m = 0; m < 4; ++m)
        #pragma unroll
        for (int n = 0; n < 4; ++n) acc[m][n] = (f32x4){0.f, 0.f, 0.f, 0.f};

    int aoff[4], boff[4];
    #pragma unroll
    for (int m = 0; m < 4; ++m) {
        int row  = wr * 64 + m * 16 + (lane & 15);
        int phys = (lane >> 4) ^ ((row ^ (row >> 2)) & 3);
        aoff[m] = row * 32 + phys * 8;
    }
    #pragma unroll
    for (int n = 0; n < 4; ++n) {
        int row  = wc * 64 + n * 16 + (lane & 15);
        int phys = (lane >> 4) ^ ((row ^ (row >> 2)) & 3);
        boff[n] = row * 32 + phys * 8;
    }

    auto stage = [&](int kk, int buf) {
        int t = kk >> 3, cic = kk & 7;
        int dy = t / 3, dx = t - dy * 3;
        const ushort_t* wtile = WbI + ((size_t)(t * 8 + cic) * 6 + by) * 4096;
        #pragma unroll
        for (int r = 0; r < 2; ++r)
            GLOAD16(wtile + r * 2048 + tid * 8, (ushort_t*)As[buf] + r * 2048 + tid * 8);
        #pragma unroll
        for (int r = 0; r < 2; ++r) {
            int p  = pB[r];
            int pr = p >> 5, c = p & 31;
            const ushort_t* src = xpI
                + ((size_t)((r0 + pr + dy) * 34 + (c + dx))) * 256
                + cic * 32 + cibase[r];
            GLOAD16(src, (ushort_t*)Bsh[buf] + r * 2048 + tid * 8);
        }
    };

    stage(0, 0);
    asm volatile("s_waitcnt vmcnt(0)" ::: "memory");
    __builtin_amdgcn_s_barrier();

    for (int kk = 0; kk < 72; ++kk) {
        int cur = kk & 1;
        if (kk < 71) stage(kk + 1, cur ^ 1);

        const ushort_t* Ab = As[cur];
        const ushort_t* Bb = Bsh[cur];
        bf16x8 af[4], bfr[4];
        #pragma unroll
        for (int m = 0; m < 4; ++m) af[m] = *(const bf16x8*)(Ab + aoff[m]);
        #pragma unroll
        for (int n = 0; n < 4; ++n) bfr[n] = *(const bf16x8*)(Bb + boff[n]);

        #pragma unroll
        for (int m = 0; m < 4; ++m)
            #pragma unroll
            for (int n = 0; n < 4; ++n)
                acc[m][n] = __builtin_amdgcn_mfma_f32_16x16x32_bf16(af[m], bfr[n], acc[m][n], 0, 0, 0);

        asm volatile("s_waitcnt vmcnt(0)" ::: "memory");
        __builtin_amdgcn_s_barrier();
    }

    const int co_base = by * 128 + wr * 64;
    const int p_base  = bx * 128 + wc * 64;
    const int rsub = (lane >> 4) * 4;
    const int csub = lane & 15;
    #pragma unroll
    for (int m = 0; m < 4; ++m) {
        #pragma unroll
        for (int rg = 0; rg < 4; ++rg) {
            int ch = co_base + m * 16 + rsub + rg;
            float bias = Bs_bias[ch];
            #pragma unroll
            for (int nn = 0; nn < 4; ++nn) {
                int p = p_base + nn * 16 + csub;
                float v = acc[m][nn][rg] + bias;
                if (ch < 256)
                    Qf[((size_t)slab * 256 + ch) * HW + p] = v * 0.17677669529663687f;
                else if (ch < 512)
                    Kb[((size_t)slab * 256 + (ch - 256)) * HW + p] = f2bf(v);
                else
                    Vb[((size_t)slab * 256 + (ch - 512)) * HW + p] = f2bf(v);
            }
        }
    }
}

// ---------------------------------------------------------------------------
// trans_kernel: build attention MFMA operand tensors.
// y: 0..95  QThi/QTlo [slab*8+n][1024 p][32 d] (hi/lo bf16 split of fp32 Q)
//    96..127 K12T[bn]  (transpose of Kb, slabs 8-11, exact)
//    128..159 KdT[bn]  (k1-k2 in fp32 from Kb, then bf16)
// x = chunk of 256 pixels. block 256.
// ---------------------------------------------------------------------------
__global__ __launch_bounds__(256) void trans_kernel(
    const float* __restrict__ Qf, const ushort_t* __restrict__ Kb,
    ushort_t* __restrict__ QThi, ushort_t* __restrict__ QTlo,
    ushort_t* __restrict__ K12T, ushort_t* __restrict__ KdT)
{
    const int z  = blockIdx.y;
    const int k0 = blockIdx.x * 256;
    const int tid = threadIdx.x;
    __shared__ float ts[32][257];

    if (z < 96) {
        int slab = z >> 3, n = z & 7;
        const float* src = Qf + ((size_t)slab * 256 + n * 32) * HW + k0;
        for (int idx = tid; idx < 8192; idx += 256) {
            int d = idx >> 8, k = idx & 255;
            ts[d][k] = src[(size_t)d * HW + k];
        }
        __syncthreads();
        ushort_t* dh = QThi + (size_t)z * 32768 + (size_t)k0 * 32;
        ushort_t* dl = QTlo + (size_t)z * 32768 + (size_t)k0 * 32;
        for (int idx = tid; idx < 8192; idx += 256) {
            int k = idx >> 5, d = idx & 31;
            float v = ts[d][k];
            ushort_t hi = f2bf(v);
            dh[(size_t)k * 32 + d] = hi;
            dl[(size_t)k * 32 + d] = f2bf(v - bf2f(hi));
        }
    } else if (z < 128) {
        int bn = z - 96, b = bn >> 3, n = bn & 7;
        const ushort_t* src = Kb + ((size_t)(8 + b) * 256 + n * 32) * HW + k0;
        for (int idx = tid; idx < 8192; idx += 256) {
            int d = idx >> 8, k = idx & 255;
            ts[d][k] = bf2f(src[(size_t)d * HW + k]);
        }
        __syncthreads();
        ushort_t* dst = K12T + (size_t)bn * 32768 + (size_t)k0 * 32;
        for (int idx = tid; idx < 8192; idx += 256) {
            int k = idx >> 5, d = idx & 31;
            dst[(size_t)k * 32 + d] = f2bf(ts[d][k]);
        }
    } else {
        int bn = z - 128, b = bn >> 3, n = bn & 7;
        const ushort_t* sA = Kb + ((size_t)b * 256 + n * 32) * HW + k0;
        const ushort_t* sB = Kb + ((size_t)(4 + b) * 256 + n * 32) * HW + k0;
        for (int idx = tid; idx < 8192; idx += 256) {
            int d = idx >> 8, k = idx & 255;
            ts[d][k] = bf2f(sA[(size_t)d * HW + k]) - bf2f(sB[(size_t)d * HW + k]);
        }
        __syncthreads();
        ushort_t* dst = KdT + (size_t)bn * 32768 + (size_t)k0 * 32;
        for (int idx = tid; idx < 8192; idx += 256) {
            int k = idx >> 5, d = idx & 31;
            dst[(size_t)k * 32 + d] = f2bf(ts[d][k]);
        }
    }
}

// ---------------------------------------------------------------------------
// rel_kernel: RW'/RH' tables from FP32 Q (full precision bias path).
// ---------------------------------------------------------------------------
__global__ __launch_bounds__(256) void rel_kernel(
    const float* __restrict__ Qf,
    const float* __restrict__ krw, const float* __restrict__ krh,
    float* __restrict__ RWp, float* __restrict__ RHp)
{
    const int tid = threadIdx.x;
    const int bn  = blockIdx.y;
    const int b   = bn >> 3, n = bn & 7;
    const int q   = blockIdx.x * 256 + tid;
    const int r   = q >> 5, c = q & 31;

    __shared__ float rwl[63 * 33 + 1];
    __shared__ float rhl[63 * 33 + 1];
    for (int idx = tid; idx < 63 * 32; idx += 256) {
        int mp = idx >> 5, d = idx & 31;
        rwl[mp * 33 + d] = krw[idx];
        rhl[mp * 33 + d] = krh[idx];
    }
    __syncthreads();

    float qv[32];
    const float* qp = Qf + ((size_t)b * 256 + n * 32) * HW;   // img0 slab = b
    #pragma unroll
    for (int d = 0; d < 32; ++d) qv[d] = qp[(size_t)d * HW + q];

    float* rw = RWp + ((size_t)bn * 1024 + q) * 32;
    float* rh = RHp + ((size_t)bn * 1024 + q) * 32;
    #pragma unroll
    for (int m = 0; m < 32; ++m) {
        const float* t1 = rwl + (m + 31 - c) * 33;
        const float* t2 = rhl + (m + 31 - r) * 33;
        float s1 = 0.f, s2 = 0.f;
        #pragma unroll
        for (int d = 0; d < 32; ++d) { s1 = fmaf(qv[d], t1[d], s1); s2 = fmaf(qv[d], t2[d], s2); }
        rw[m] = s1;
        rh[m] = s2;
    }
}

// ---------------------------------------------------------------------------
// attn_mfma: flash attention, swapped operands (S^T = K x Q), with
// Q hi/lo split (2x QK MFMA) and P hi/lo split (2x PV MFMA) for precision.
// ---------------------------------------------------------------------------
__global__ __launch_bounds__(256) void attn_mfma_kernel(
    const ushort_t* __restrict__ QThi, const ushort_t* __restrict__ QTlo,
    const ushort_t* __restrict__ K12T, const ushort_t* __restrict__ KdT,
    const ushort_t* __restrict__ Vb,
    const float* __restrict__ RWp, const float* __restrict__ RHp,
    float* __restrict__ yw)
{
    const int qt = blockIdx.x;
    const int bn = blockIdx.y;
    const int br = blockIdx.z;
    const int b  = bn >> 3, n = bn & 7;
    const int tid = threadIdx.x, lane = tid & 63, wid = tid >> 6;
    const int q0 = qt * 128;

    __shared__ ushort_t qt_l[2][4096];     // [hi/lo][128 q][32 d] linear
    __shared__ ushort_t kt_l[2][2048];     // [64 k][32 d] linear (dbuf)
    __shared__ ushort_t v_l[2][2048];      // [32 d][64 k], chunk^(d&7) (dbuf)
    __shared__ ushort_t p_l[4][4096];      // per-wave [hi | lo], each [32 q][64 k]

    const int slab = br * 4 + b;
    const size_t qoff = ((size_t)(slab * 8 + n) * 1024 + q0) * 32;
    const ushort_t* KTb = ((br == 2) ? KdT : K12T) + (size_t)bn * 32768;
    const ushort_t* Vg  = Vb + ((size_t)slab * 256 + n * 32) * HW;

    GLOAD16((const char*)(QThi + qoff) + tid * 16,        (char*)qt_l[0] + tid * 16);
    GLOAD16((const char*)(QThi + qoff) + 4096 + tid * 16, (char*)qt_l[0] + 4096 + tid * 16);
    GLOAD16((const char*)(QTlo + qoff) + tid * 16,        (char*)qt_l[1] + tid * 16);
    GLOAD16((const char*)(QTlo + qoff) + 4096 + tid * 16, (char*)qt_l[1] + 4096 + tid * 16);

    const int vd = tid >> 3, vpc = tid & 7;
    const char* Vrow = (const char*)Vg + (size_t)vd * 2048 + ((vpc ^ (vd & 7)) * 16);
    auto stage = [&](int t, int buf) {
        GLOAD16((const char*)KTb + t * 4096 + tid * 16, (char*)kt_l[buf] + tid * 16);
        GLOAD16(Vrow + t * 128,                          (char*)v_l[buf] + tid * 16);
    };
    stage(0, 0);

    float rwc[2][8];
    if (br == 0) {
        #pragma unroll
        for (int m = 0; m < 2; ++m) {
            int q = q0 + wid * 32 + m * 16 + (lane & 15);
            const float* rwp = RWp + ((size_t)bn * 1024 + q) * 32;
            #pragma unroll
            for (int i = 0; i < 2; ++i)
                #pragma unroll
                for (int r = 0; r < 4; ++r)
                    rwc[m][i * 4 + r] = rwp[i * 16 + 4 * (lane >> 4) + r];
        }
    }

    asm volatile("s_waitcnt vmcnt(0)" ::: "memory");
    __builtin_amdgcn_s_barrier();

    bf16x8 qfh[2], qfl[2];
    #pragma unroll
    for (int m = 0; m < 2; ++m) {
        int off = (wid * 32 + m * 16 + (lane & 15)) * 32 + (lane >> 4) * 8;
        qfh[m] = *(const bf16x8*)(qt_l[0] + off);
        qfl[m] = *(const bf16x8*)(qt_l[1] + off);
    }

    f32x4 oacc[2][2];
    #pragma unroll
    for (int ds = 0; ds < 2; ++ds)
        #pragma unroll
        for (int m = 0; m < 2; ++m) oacc[ds][m] = (f32x4){0.f, 0.f, 0.f, 0.f};
    float m_run[2] = {-INFINITY, -INFINITY}, l_run[2] = {0.f, 0.f};
    const f32x4 zero4 = (f32x4){0.f, 0.f, 0.f, 0.f};

    for (int t = 0; t < 16; ++t) {
        int cur = t & 1;

        float rh[2][2];
        if (br == 0) {
            #pragma unroll
            for (int m = 0; m < 2; ++m) {
                int q = q0 + wid * 32 + m * 16 + (lane & 15);
                const float* rhp = RHp + ((size_t)bn * 1024 + q) * 32 + 2 * t;
                rh[m][0] = rhp[0];
                rh[m][1] = rhp[1];
            }
        }
        if (t < 15) stage(t + 1, cur ^ 1);

        bf16x8 kf[4];
        #pragma unroll
        for (int s = 0; s < 4; ++s)
            kf[s] = *(const bf16x8*)(kt_l[cur] + (s * 16 + (lane & 15)) * 32 + (lane >> 4) * 8);

        f32x4 sa[4][2];
        #pragma unroll
        for (int s = 0; s < 4; ++s)
            #pragma unroll
            for (int m = 0; m < 2; ++m) {
                sa[s][m] = __builtin_amdgcn_mfma_f32_16x16x32_bf16(kf[s], qfl[m], zero4, 0, 0, 0);
                sa[s][m] = __builtin_amdgcn_mfma_f32_16x16x32_bf16(kf[s], qfh[m], sa[s][m], 0, 0, 0);
            }

        if (br == 0) {
            #pragma unroll
            for (int s = 0; s < 4; ++s)
                #pragma unroll
                for (int m = 0; m < 2; ++m)
                    #pragma unroll
                    for (int r = 0; r < 4; ++r)
                        sa[s][m][r] += rwc[m][(s & 1) * 4 + r] + rh[m][s >> 1];
        }

        #pragma unroll
        for (int m = 0; m < 2; ++m) {
            float mx = sa[0][m][0];
            #pragma unroll
            for (int s = 0; s < 4; ++s)
                #pragma unroll
                for (int r = 0; r < 4; ++r) mx = fmaxf(mx, sa[s][m][r]);
            mx = fmaxf(mx, __shfl_xor(mx, 16));
            mx = fmaxf(mx, __shfl_xor(mx, 32));
            float mnew = fmaxf(m_run[m], mx);
            float sc = __expf(m_run[m] - mnew);
            float ps = 0.f;
            #pragma unroll
            for (int s = 0; s < 4; ++s)
                #pragma unroll
                for (int r = 0; r < 4; ++r) {
                    float p = __expf(sa[s][m][r] - mnew);
                    sa[s][m][r] = p;
                    ps += p;
                }
            ps += __shfl_xor(ps, 16);
            ps += __shfl_xor(ps, 32);
            l_run[m] = l_run[m] * sc + ps;
            m_run[m] = mnew;
            oacc[0][m] = oacc[0][m] * sc;
            oacc[1][m] = oacc[1][m] * sc;
        }

        // P -> bf16 hi/lo -> per-wave LDS (chunk-XOR swizzle)
        const int g = lane >> 4;
        #pragma unroll
        for (int s = 0; s < 4; ++s)
            #pragma unroll
            for (int m = 0; m < 2; ++m) {
                int qrow = m * 16 + (lane & 15);
                int chunk = (2 * s + (g >> 1)) ^ (qrow & 7);
                char* basep = (char*)p_l[wid] + qrow * 128 + chunk * 16 + 8 * (g & 1);
                #pragma unroll
                for (int h = 0; h < 2; ++h) {
                    float pa = sa[s][m][2 * h], pb = sa[s][m][2 * h + 1];
                    ushort_t ha = f2bf(pa), hb = f2bf(pb);
                    ushort_t la = f2bf(pa - bf2f(ha)), lb = f2bf(pb - bf2f(hb));
                    *(unsigned*)(basep + 4 * h)        = (unsigned)ha | ((unsigned)hb << 16);
                    *(unsigned*)(basep + 4096 + 4 * h) = (unsigned)la | ((unsigned)lb << 16);
                }
            }

        // PV: O^T += V^T x (P_hi + P_lo)
        #pragma unroll
        for (int ks = 0; ks < 2; ++ks) {
            bf16x8 vf[2], pfh[2], pfl[2];
            #pragma unroll
            for (int ds = 0; ds < 2; ++ds) {
                int drow = ds * 16 + (lane & 15);
                int chunk = (4 * ks + g) ^ (drow & 7);
                vf[ds] = *(const bf16x8*)((char*)v_l[cur] + drow * 128 + chunk * 16);
            }
            #pragma unroll
            for (int m = 0; m < 2; ++m) {
                int qrow = m * 16 + (lane & 15);
                int chunk = (4 * ks + g) ^ (qrow & 7);
                pfh[m] = *(const bf16x8*)((char*)p_l[wid] + qrow * 128 + chunk * 16);
                pfl[m] = *(const bf16x8*)((char*)p_l[wid] + 4096 + qrow * 128 + chunk * 16);
            }
            #pragma unroll
            for (int ds = 0; ds < 2; ++ds)
                #pragma unroll
                for (int m = 0; m < 2; ++m) {
                    oacc[ds][m] = __builtin_amdgcn_mfma_f32_16x16x32_bf16(vf[ds], pfh[m], oacc[ds][m], 0, 0, 0);
                    oacc[ds][m] = __builtin_amdgcn_mfma_f32_16x16x32_bf16(vf[ds], pfl[m], oacc[ds][m], 0, 0, 0);
                }
        }

        asm volatile("s_waitcnt vmcnt(0)" ::: "memory");
        __builtin_amdgcn_s_barrier();
    }

    #pragma unroll
    for (int m = 0; m < 2; ++m) {
        float inv = 1.0f / l_run[m];
        int q = q0 + wid * 32 + m * 16 + (lane & 15);
        int rr = q >> 5, cc = q & 31;
        float* yb = yw + ((size_t)((br * 4 + b) * 256 + n * 32 + rr)) * HW + cc * 32;
        #pragma unroll
        for (int ds = 0; ds < 2; ++ds) {
            int dbase = ds * 16 + (lane >> 4) * 4;
            float4 o = make_float4(oacc[ds][m][0] * inv, oacc[ds][m][1] * inv,
                                   oacc[ds][m][2] * inv, oacc[ds][m][3] * inv);
            *reinterpret_cast<float4*>(yb + dbase) = o;
        }
    }
}

// ---------------------------------------------------------------------------
// conv1x1: unchanged (reads fp32 yw).
// ---------------------------------------------------------------------------
__global__ __launch_bounds__(256) void conv1x1_kernel(
    const float* __restrict__ yw, const float* __restrict__ Wo,
    const float* __restrict__ bo, float* __restrict__ out)
{
    const int co0  = blockIdx.x * 16;
    const int p0   = blockIdx.y * 256;
    const int slab = blockIdx.z;
    const float* yb = yw + (size_t)slab * 256 * HW;
    float* ob       = out + (size_t)slab * 256 * HW;

    __shared__ float ys[32][256];
    __shared__ float wsl[32][16];

    const int tid = threadIdx.x;
    float acc[16];
    #pragma unroll
    for (int co = 0; co < 16; ++co) acc[co] = 0.f;

    for (int ci0 = 0; ci0 < 256; ci0 += 32) {
        __syncthreads();
        for (int idx = tid; idx < 32 * 256; idx += 256) {
            int ci = idx >> 8, p = idx & 255;
            ys[ci][p] = yb[(size_t)(ci0 + ci) * HW + p0 + p];
        }
        for (int idx = tid; idx < 512; idx += 256) {
            int ci = idx >> 4, co = idx & 15;
            wsl[ci][co] = Wo[(size_t)(co0 + co) * 256 + ci0 + ci];
        }
        __syncthreads();
        #pragma unroll
        for (int ci = 0; ci < 32; ++ci) {
            float xv = ys[ci][tid];
            const float4* wp = reinterpret_cast<const float4*>(&wsl[ci][0]);
            float4 w0 = wp[0], w1 = wp[1], w2 = wp[2], w3 = wp[3];
            acc[0]  = fmaf(w0.x, xv, acc[0]);  acc[1]  = fmaf(w0.y, xv, acc[1]);
            acc[2]  = fmaf(w0.z, xv, acc[2]);  acc[3]  = fmaf(w0.w, xv, acc[3]);
            acc[4]  = fmaf(w1.x, xv, acc[4]);  acc[5]  = fmaf(w1.y, xv, acc[5]);
            acc[6]  = fmaf(w1.z, xv, acc[6]);  acc[7]  = fmaf(w1.w, xv, acc[7]);
            acc[8]  = fmaf(w2.x, xv, acc[8]);  acc[9]  = fmaf(w2.y, xv, acc[9]);
            acc[10] = fmaf(w2.z, xv, acc[10]); acc[11] = fmaf(w2.w, xv, acc[11]);
            acc[12] = fmaf(w3.x, xv, acc[12]); acc[13] = fmaf(w3.y, xv, acc[13]);
            acc[14] = fmaf(w3.z, xv, acc[14]); acc[15] = fmaf(w3.w, xv, acc[15]);
        }
    }
    #pragma unroll
    for (int co = 0; co < 16; ++co)
        ob[(size_t)(co0 + co) * HW + p0 + tid] = acc[co] + bo[co0 + co];
}

// ---------------------------------------------------------------------------
extern "C" void kernel_launch(void* const* d_in, const int* in_sizes, int n_in,
                              void* d_out, int out_size, void* d_ws, size_t ws_size,
                              hipStream_t stream)
{
    const float* x1   = (const float*)d_in[0];
    const float* x2   = (const float*)d_in[1];
    const float* x12  = (const float*)d_in[2];
    const float* Wq1  = (const float*)d_in[3];
    const float* bq1  = (const float*)d_in[4];
    const float* Wq2  = (const float*)d_in[5];
    const float* bq2  = (const float*)d_in[6];
    const float* Wq12 = (const float*)d_in[7];
    const float* bq12 = (const float*)d_in[8];
    const float* Wo   = (const float*)d_in[9];
    const float* bo   = (const float*)d_in[10];
    const float* krw  = (const float*)d_in[11];
    const float* krh  = (const float*)d_in[12];

    // workspace (50,331,648 B total; R2 proved >= 55,468,032 available):
    //   0         Qf fp32 [12][256][1024]   12,582,912  (yw aliases after rel+trans)
    //   12582912  Kb bf16 [12][256][1024]    6,291,456  (dead after trans)
    //   18874368  Vb bf16 [12][256][1024]    6,291,456  (live till attn)
    //   25165824  QThi bf16                  6,291,456  \
    //   31457280  QTlo bf16                  6,291,456   | trans outputs
    //   37748736  K12T bf16                  2,097,152   | (Wb @25165824 and
    //   39845888  KdT  bf16                  2,097,152   |  xpadT @35782656
    //   41943040  RWp  f32                   4,194,304   |  alias here; dead
    //   46137344  RHp  f32                   4,194,304  /   after conv)
    char* base = (char*)d_ws;
    float*    Qf    = (float*)base;
    float*    yw    = (float*)base;                      // alias: attn out
    ushort_t* Kb    = (ushort_t*)(base + 12582912);
    ushort_t* Vb    = (ushort_t*)(base + 18874368);
    ushort_t* QThi  = (ushort_t*)(base + 25165824);
    ushort_t* QTlo  = (ushort_t*)(base + 31457280);
    ushort_t* K12T  = (ushort_t*)(base + 37748736);
    ushort_t* KdT   = (ushort_t*)(base + 39845888);
    float*    RWp   = (float*)(base + 41943040);
    float*    RHp   = (float*)(base + 46137344);
    ushort_t* Wb    = (ushort_t*)(base + 25165824);      // alias, dead after conv
    ushort_t* xpadT = (ushort_t*)(base + 35782656);      // alias, dead after conv
    float*    outf  = (float*)d_out;

    const size_t xpad_bytes = (size_t)12 * 34 * 34 * 256 * 2;
    hipMemsetAsync(xpadT, 0, xpad_bytes, stream);

    hipLaunchKernelGGL(prep_x_kernel, dim3(32, 12), dim3(256), 0, stream,
                       x1, x2, x12, xpadT);
    hipLaunchKernelGGL(prep_w_kernel, dim3(2304), dim3(256), 0, stream,
                       Wq1, Wq2, Wq12, Wb);
    hipLaunchKernelGGL(conv_mfma_kernel, dim3(8, 6, 12), dim3(256), 0, stream,
                       Wb, xpadT, bq1, bq2, bq12, Qf, Kb, Vb);
    hipLaunchKernelGGL(trans_kernel, dim3(4, 160), dim3(256), 0, stream,
                       Qf, Kb, QThi, QTlo, K12T, KdT);
    hipLaunchKernelGGL(rel_kernel, dim3(4, 32), dim3(256), 0, stream,
                       Qf, krw, krh, RWp, RHp);
    hipLaunchKernelGGL(attn_mfma_kernel, dim3(8, 32, 3), dim3(256), 0, stream,
                       QThi, QTlo, K12T, KdT, Vb, RWp, RHp, yw);
    hipLaunchKernelGGL(conv1x1_kernel, dim3(16, 4, 12), dim3(256), 0, stream,
                       yw, Wo, bo, outf);
}